// Round 6
// baseline (54.169 us; speedup 1.0000x reference)
//
#include <hip/hip_runtime.h>

// d2 (B=32, L=2048, K=512) fp32.
// z_t = clip(0.9*z_{t-1} + 0.1*d2_t, 0, 5), z_{-1}=0, scan over t.
//
// Chunked scan + truncated look-back warmup (W=64: measured absmax 3.9e-3
// vs threshold 1.63e-2; inputs are uniform[0,1) so z<1 and the clamp never
// binds -> truncation error 0.9^W exactly).
//
// Round-5 design point — TLP test:
//  - r1-r4 all ran 2048 waves and all plateaued at 4.3-4.4 TB/s regardless
//    of load width / prefetch depth -> per-wave MLP is not the limiter.
//  - NC=16 with SCALAR loads doubles threads: 262144 = 4096 waves =
//    16 waves/CU (4/SIMD). Cost: 1.5x read redundancy (FETCH ~96 MB,
//    measured in r3) vs r1's 1.25x.
//  - unroll 16 keeps ~16 loads in flight per wave (r4 showed compiler
//    handles this fine at VGPR~36).

constexpr int B  = 32;
constexpr int L  = 2048;
constexpr int K  = 512;
constexpr int NC = 16;           // chunks along L
constexpr int C  = L / NC;       // 128
constexpr int W  = 64;           // warmup steps (0.9^64 ~ 1.2e-3)

__global__ __launch_bounds__(256)
void ema_tlp_kernel(const float* __restrict__ d2, float* __restrict__ out) {
    const float lam = 0.9f, om = 0.1f, zmax = 5.0f;

    int tid = blockIdx.x * blockDim.x + threadIdx.x;   // B*NC*K = 262144
    int k   = tid & (K - 1);
    int bc  = tid >> 9;          // / K
    int c   = bc & (NC - 1);
    int b   = bc >> 4;           // / NC

    const float* in = d2  + (size_t)b * L * K + k;
    float*       o  = out + (size_t)b * L * K + k;

    int t0 = c * C;
    int tw = t0 - W;
    if (tw < 0) tw = 0;

    float z = 0.0f;

    // warmup (no stores)
    #pragma unroll 16
    for (int t = tw; t < t0; ++t) {
        float d = in[(size_t)t * K];
        z = fminf(fmaxf(lam * z + om * d, 0.0f), zmax);
    }

    // main chunk
    #pragma unroll 16
    for (int t = t0; t < t0 + C; ++t) {
        float d = in[(size_t)t * K];
        z = fminf(fmaxf(lam * z + om * d, 0.0f), zmax);
        o[(size_t)t * K] = z;
    }
}

extern "C" void kernel_launch(void* const* d_in, const int* in_sizes, int n_in,
                              void* d_out, int out_size, void* d_ws, size_t ws_size,
                              hipStream_t stream) {
    const float* d2 = (const float*)d_in[0];
    float* out = (float*)d_out;

    int total = B * NC * K;                 // 262144 threads
    int block = 256;
    int grid  = total / block;              // 1024 blocks
    ema_tlp_kernel<<<grid, block, 0, stream>>>(d2, out);
}

// Round 7
// 46.139 us; speedup vs baseline: 1.1741x; 1.1741x over previous
//
#include <hip/hip_runtime.h>

// d2 (B=32, L=2048, K=512) fp32.
// z_t = clip(0.9*z_{t-1} + 0.1*d2_t, 0, 5), z_{-1}=0, scan over t.
//
// Chunked scan + truncated look-back warmup. Round-6 design point.
//
// Empirical law from r1-r5 (width, TLP, prefetch all null):
//     dur = (logical reads + writes) / ~6.0 TB/s   (fabric/HBM ceiling,
//     = m13 copy ceiling within 5%).
// => only lever left is traffic. Writes fixed at 134 MB. Reads =
//    128 MB * (1 + (NC-1)*W/L). NC=8 -> 156 MB; NC=4 -> 140 MB.
// This round: NC=4 (C=512), W=64 (absmax 3.9e-3 vs thr 1.63e-2).
// 65536 threads = 1024 waves = 4/CU; r2 showed 1024 waves still meets
// the traffic law. unroll 32 keeps >=32 loads in flight per wave.

constexpr int B  = 32;
constexpr int L  = 2048;
constexpr int K  = 512;
constexpr int NC = 4;            // chunks along L
constexpr int C  = L / NC;       // 512
constexpr int W  = 64;           // warmup steps (0.9^64 ~ 1.2e-3)

__global__ __launch_bounds__(256)
void ema_nc4_kernel(const float* __restrict__ d2, float* __restrict__ out) {
    const float lam = 0.9f, om = 0.1f, zmax = 5.0f;

    int tid = blockIdx.x * blockDim.x + threadIdx.x;   // B*NC*K = 65536
    int k   = tid & (K - 1);
    int bc  = tid >> 9;          // / K
    int c   = bc & (NC - 1);
    int b   = bc >> 2;           // / NC

    const float* in = d2  + (size_t)b * L * K + k;
    float*       o  = out + (size_t)b * L * K + k;

    int t0 = c * C;
    int tw = t0 - W;
    if (tw < 0) tw = 0;

    float z = 0.0f;

    // warmup (no stores): 64 iters = 2 unroll blocks
    #pragma unroll 32
    for (int t = tw; t < t0; ++t) {
        float d = in[(size_t)t * K];
        z = fminf(fmaxf(lam * z + om * d, 0.0f), zmax);
    }

    // main chunk: 512 iters = 16 unroll blocks
    #pragma unroll 32
    for (int t = t0; t < t0 + C; ++t) {
        float d = in[(size_t)t * K];
        z = fminf(fmaxf(lam * z + om * d, 0.0f), zmax);
        o[(size_t)t * K] = z;
    }
}

extern "C" void kernel_launch(void* const* d_in, const int* in_sizes, int n_in,
                              void* d_out, int out_size, void* d_ws, size_t ws_size,
                              hipStream_t stream) {
    const float* d2 = (const float*)d_in[0];
    float* out = (float*)d_out;

    int total = B * NC * K;                 // 65536 threads
    int block = 256;
    int grid  = total / block;              // 256 blocks
    ema_nc4_kernel<<<grid, block, 0, stream>>>(d2, out);
}